// Round 4
// baseline (392.367 us; speedup 1.0000x reference)
//
#include <hip/hip_runtime.h>
#include <hip/hip_bf16.h>
#include <math.h>

typedef __bf16 bf16_t;
typedef bf16_t bf16x8 __attribute__((ext_vector_type(8)));
typedef bf16_t bf16x4v __attribute__((ext_vector_type(4)));
typedef float f32x4 __attribute__((ext_vector_type(4)));

#define S_LEN 2048
#define HDIM 2048
#define QKV_LD 3072

// ---------------- cast fp32 -> bf16 (vectorized) ----------------
__global__ __launch_bounds__(256) void cast_bf16_kernel(const float* __restrict__ in,
                                                        bf16_t* __restrict__ out, int n4) {
  int i = blockIdx.x * 256 + threadIdx.x;
  if (i >= n4) return;
  float4 v = ((const float4*)in)[i];
  bf16x4v o;
  o[0] = (bf16_t)v.x; o[1] = (bf16_t)v.y; o[2] = (bf16_t)v.z; o[3] = (bf16_t)v.w;
  ((bf16x4v*)out)[i] = o;
}

// ---------------- transpose + cast: in (K x N) fp32 -> out (N x K) bf16 ----------------
__global__ __launch_bounds__(256) void transpose_cast_kernel(const float* __restrict__ in,
                                                             bf16_t* __restrict__ out,
                                                             int K, int N) {
  __shared__ float tile[32][33];
  int n0 = blockIdx.x * 32, k0 = blockIdx.y * 32;
  int tx = threadIdx.x & 31, ty = threadIdx.x >> 5;
#pragma unroll
  for (int i = 0; i < 4; ++i)
    tile[ty + i * 8][tx] = in[(size_t)(k0 + ty + i * 8) * N + n0 + tx];
  __syncthreads();
#pragma unroll
  for (int i = 0; i < 4; ++i)
    out[(size_t)(n0 + ty + i * 8) * K + k0 + tx] = (bf16_t)tile[tx][ty + i * 8];
}

// ---------------- V^T extraction: VT[v=hk*128+d][s] = qkv[s][2560+v] ----------------
__global__ __launch_bounds__(256) void vtrans_kernel(const bf16_t* __restrict__ qkv,
                                                     bf16_t* __restrict__ vt) {
  __shared__ bf16_t tile[32][33];
  int v0 = blockIdx.x * 32, s0 = blockIdx.y * 32;
  int tx = threadIdx.x & 31, ty = threadIdx.x >> 5;
#pragma unroll
  for (int i = 0; i < 4; ++i)
    tile[ty + i * 8][tx] = qkv[(size_t)(s0 + ty + i * 8) * QKV_LD + 2560 + v0 + tx];
  __syncthreads();
#pragma unroll
  for (int i = 0; i < 4; ++i)
    vt[(size_t)(v0 + ty + i * 8) * S_LEN + s0 + tx] = tile[tx][ty + i * 8];
}

// ---------------- block reduction helper (blockDim == 256) ----------------
__device__ __forceinline__ float block_reduce_256(float v, float* red) {
  int tid = threadIdx.x;
  red[tid] = v;
  __syncthreads();
  for (int off = 128; off > 0; off >>= 1) {
    if (tid < off) red[tid] += red[tid + off];
    __syncthreads();
  }
  float r = red[0];
  __syncthreads();
  return r;
}

// ---------------- LayerNorm + gate (one block per row) ----------------
__global__ __launch_bounds__(256) void ln_gate_kernel(const float* __restrict__ hs,
                                                      const float* __restrict__ gw,
                                                      const float* __restrict__ gb,
                                                      const float* __restrict__ lng,
                                                      const float* __restrict__ lnb,
                                                      float* __restrict__ gates) {
  __shared__ float red[256];
  int row = blockIdx.x;
  const float* x = hs + (size_t)row * HDIM;
  float s = 0.f, ss = 0.f;
  for (int i = threadIdx.x * 4; i < HDIM; i += 1024) {
    float4 v = *(const float4*)(x + i);
    s += v.x + v.y + v.z + v.w;
    ss += v.x * v.x + v.y * v.y + v.z * v.z + v.w * v.w;
  }
  s = block_reduce_256(s, red);
  ss = block_reduce_256(ss, red);
  float mean = s * (1.f / HDIM);
  float var = ss * (1.f / HDIM) - mean * mean;
  float rstd = rsqrtf(var + 1e-5f);
  float dot = 0.f;
  for (int i = threadIdx.x * 4; i < HDIM; i += 1024) {
    float4 v = *(const float4*)(x + i);
    float4 g = *(const float4*)(lng + i);
    float4 b = *(const float4*)(lnb + i);
    float4 w = *(const float4*)(gw + i);
    dot += ((v.x - mean) * rstd * g.x + b.x) * w.x;
    dot += ((v.y - mean) * rstd * g.y + b.y) * w.y;
    dot += ((v.z - mean) * rstd * g.z + b.z) * w.z;
    dot += ((v.w - mean) * rstd * g.w + b.w) * w.w;
  }
  dot = block_reduce_256(dot, red);
  if (threadIdx.x == 0) {
    float gi = dot + gb[0];
    gi = fminf(10.f, fmaxf(-10.f, gi));
    gates[row] = 1.f / (1.f + __expf(-gi));
  }
}

// ---------------- regularization loss (single block) -> fp32 scalar ----------------
__global__ __launch_bounds__(256) void reg_loss_kernel(const float* __restrict__ gates,
                                                       float* __restrict__ out) {
  __shared__ float red[256];
  float sb = 0.f, se = 0.f, sg = 0.f;
  for (int i = threadIdx.x; i < S_LEN; i += 256) {
    float g = gates[i];
    float gc = fminf(1.f - 1e-5f, fmaxf(1e-5f, g));
    sb += g * (1.f - g);
    se += g * logf(gc) + (1.f - g) * logf(1.f - gc);
    sg += g;
  }
  sb = block_reduce_256(sb, red);
  se = block_reduce_256(se, red);
  sg = block_reduce_256(sg, red);
  if (threadIdx.x == 0) {
    const float inv = 1.f / (float)S_LEN;
    float reg = -0.1f * (sb * inv) - 0.01f * (se * inv) + 0.1f * (sg * inv);
    out[0] = reg;
  }
}

// ---------------- bf16 GEMM: C(MxN) = A(MxK) * Bt(NxK)^T, all row-major ----------------
template <typename OutT>
__global__ __launch_bounds__(256) void gemm_bt_kernel(const bf16_t* __restrict__ A,
                                                      const bf16_t* __restrict__ Bt,
                                                      OutT* __restrict__ C,
                                                      int M, int N, int K) {
  __shared__ bf16_t As[128][32];
  __shared__ bf16_t Bs[128][32];
  int tid = threadIdx.x;
  int lane = tid & 63, wave = tid >> 6;
  int wr = wave >> 1, wc = wave & 1;
  int m0 = blockIdx.y * 128, n0 = blockIdx.x * 128;
  int lrow = lane & 15, lhi = lane >> 4;
  f32x4 acc[4][4];
#pragma unroll
  for (int a = 0; a < 4; ++a)
#pragma unroll
    for (int b = 0; b < 4; ++b)
#pragma unroll
      for (int r = 0; r < 4; ++r) acc[a][b][r] = 0.f;

  for (int k0 = 0; k0 < K; k0 += 32) {
    __syncthreads();
#pragma unroll
    for (int i = 0; i < 2; ++i) {
      int c = tid * 2 + i;
      int rr = c >> 2, kk = (c & 3) * 8;
      *(uint4*)(&As[rr][kk]) = *(const uint4*)(A + (size_t)(m0 + rr) * K + k0 + kk);
      *(uint4*)(&Bs[rr][kk]) = *(const uint4*)(Bt + (size_t)(n0 + rr) * K + k0 + kk);
    }
    __syncthreads();
    bf16x8 af[4], bfr[4];
#pragma unroll
    for (int a = 0; a < 4; ++a)
      af[a] = *(const bf16x8*)(&As[wr * 64 + a * 16 + lrow][lhi * 8]);
#pragma unroll
    for (int b = 0; b < 4; ++b)
      bfr[b] = *(const bf16x8*)(&Bs[wc * 64 + b * 16 + lrow][lhi * 8]);
#pragma unroll
    for (int a = 0; a < 4; ++a)
#pragma unroll
      for (int b = 0; b < 4; ++b)
        acc[a][b] = __builtin_amdgcn_mfma_f32_16x16x32_bf16(af[a], bfr[b], acc[a][b], 0, 0, 0);
  }
#pragma unroll
  for (int a = 0; a < 4; ++a)
#pragma unroll
    for (int b = 0; b < 4; ++b)
#pragma unroll
      for (int r = 0; r < 4; ++r) {
        int row = m0 + wr * 64 + a * 16 + lhi * 4 + r;
        int col = n0 + wc * 64 + b * 16 + lrow;
        C[(size_t)row * N + col] = (OutT)acc[a][b][r];
      }
}

// ---------------- dual-softmax flash attention v3 ----------------
// No K/V LDS staging: K B-frags and V^T A-frags straight from global (L1/L2-resident,
// 64B-line-friendly). PV computes O^T = V^T * P^T so V is consumed row-contiguous.
// Waves fully independent (no __syncthreads). Per-wave P / esc / l bounce through
// tiny LDS (wave-lockstep, ~2-way banks).
__global__ __launch_bounds__(256, 2) void attn_kernel(const bf16_t* __restrict__ QKV,
                                                      const bf16_t* __restrict__ VTg,
                                                      const float* __restrict__ gates,
                                                      bf16_t* __restrict__ out) {
  __shared__ bf16_t Pg[4][16][72];
  __shared__ bf16_t Pl[4][16][72];
  __shared__ float Eb[4][2][16];   // per-tile rescale factors, sc-layout -> q-layout
  __shared__ float Lb[4][2][16];   // final 1/l denominators

  int b = blockIdx.x;
  int h = b & 15;
  int t5 = b >> 4;
  int c = (t5 < 16) ? (31 - t5) : (t5 - 16);  // pair c with 31-c for load balance
  int q0c = c * 64;
  int tid = threadIdx.x;
  int lane = tid & 63, w = tid >> 6;
  int lrow = lane & 15, lhi = lane >> 4;
  int q0w = q0c + w * 16;
  int hk = h & 3;
  const bf16_t* Qp = QKV + h * 128;
  const bf16_t* Kp = QKV + 2048 + hk * 128;
  const bf16_t* Vt = VTg + (size_t)hk * 128 * S_LEN;

  // Q A-fragments: lane holds Q[q0w+lrow][ks*32 + lhi*8 ..+8]
  bf16x8 aq[4];
#pragma unroll
  for (int ks = 0; ks < 4; ++ks)
    aq[ks] = *(const bf16x8*)(Qp + (size_t)(q0w + lrow) * QKV_LD + ks * 32 + lhi * 8);

  float mg[4], ml[4], lg[4], ll[4];
  f32x4 og[8], ol[8];  // O^T accumulators: row = d-dim (dblk*16+lhi*4+r), col q = lrow
#pragma unroll
  for (int r = 0; r < 4; ++r) { mg[r] = ml[r] = -1e30f; lg[r] = ll[r] = 0.f; }
#pragma unroll
  for (int d = 0; d < 8; ++d)
#pragma unroll
    for (int r = 0; r < 4; ++r) { og[d][r] = 0.f; ol[d][r] = 0.f; }

  const float NEGINF = -__builtin_inff();
  const float scl = 0.08838834764831845f;  // 1/sqrt(128)
  int kend = q0c + 128;
  if (kend > S_LEN) kend = S_LEN;
  int nt = kend >> 6;

  for (int ti = 0; ti < nt; ++ti) {
    int k0 = ti << 6;

    // ---- QK^T: 16q x 64k, K B-frags from global ----
    f32x4 sc[4];
#pragma unroll
    for (int t = 0; t < 4; ++t) {
#pragma unroll
      for (int r = 0; r < 4; ++r) sc[t][r] = 0.f;
    }
#pragma unroll
    for (int t = 0; t < 4; ++t) {
      const bf16_t* krow = Kp + (size_t)(k0 + t * 16 + lrow) * QKV_LD + lhi * 8;
#pragma unroll
      for (int ks = 0; ks < 4; ++ks) {
        bf16x8 bk = *(const bf16x8*)(krow + ks * 32);
        sc[t] = __builtin_amdgcn_mfma_f32_16x16x32_bf16(aq[ks], bk, sc[t], 0, 0, 0);
      }
    }

    bool g_act = (k0 <= q0w + 15);
    bool g_full = (k0 + 63 <= q0w);
    bool l_act = (k0 + 63 >= q0w - 64) && (k0 <= q0w + 79);

    // ---- global (causal) softmax ----
    if (g_act) {
#pragma unroll
      for (int r = 0; r < 4; ++r) {
        int i = q0w + lhi * 4 + r;
        float v0, v1, v2, v3;
        if (g_full) {
          v0 = sc[0][r] * scl; v1 = sc[1][r] * scl;
          v2 = sc[2][r] * scl; v3 = sc[3][r] * scl;
        } else {
          int j = k0 + lrow;
          v0 = (j > i) ? NEGINF : sc[0][r] * scl;
          v1 = (j + 16 > i) ? NEGINF : sc[1][r] * scl;
          v2 = (j + 32 > i) ? NEGINF : sc[2][r] * scl;
          v3 = (j + 48 > i) ? NEGINF : sc[3][r] * scl;
        }
        float rmax = fmaxf(fmaxf(v0, v1), fmaxf(v2, v3));
#pragma unroll
        for (int m = 1; m < 16; m <<= 1) rmax = fmaxf(rmax, __shfl_xor(rmax, m, 64));
        float mnew = fmaxf(mg[r], rmax);
        float esc = __expf(mg[r] - mnew);
        float p0 = __expf(v0 - mnew), p1 = __expf(v1 - mnew);
        float p2 = __expf(v2 - mnew), p3 = __expf(v3 - mnew);
        int pr = lhi * 4 + r;
        Pg[w][pr][lrow] = (bf16_t)p0;
        Pg[w][pr][16 + lrow] = (bf16_t)p1;
        Pg[w][pr][32 + lrow] = (bf16_t)p2;
        Pg[w][pr][48 + lrow] = (bf16_t)p3;
        float ps = (p0 + p1) + (p2 + p3);
#pragma unroll
        for (int m = 1; m < 16; m <<= 1) ps += __shfl_xor(ps, m, 64);
        lg[r] = lg[r] * esc + ps;
        mg[r] = mnew;
        if (lrow == 0) Eb[w][0][pr] = esc;  // publish rescale in q-index order
      }
    }

    // ---- local (band) softmax ----
    if (l_act) {
#pragma unroll
      for (int r = 0; r < 4; ++r) {
        int i = q0w + lhi * 4 + r;
        int j = k0 + lrow;
        int d0 = i - j, d1 = d0 - 16, d2 = d0 - 32, d3 = d0 - 48;
        float v0 = (d0 > 64 || d0 < -64) ? NEGINF : sc[0][r] * scl;
        float v1 = (d1 > 64 || d1 < -64) ? NEGINF : sc[1][r] * scl;
        float v2 = (d2 > 64 || d2 < -64) ? NEGINF : sc[2][r] * scl;
        float v3 = (d3 > 64 || d3 < -64) ? NEGINF : sc[3][r] * scl;
        float rmax = fmaxf(fmaxf(v0, v1), fmaxf(v2, v3));
#pragma unroll
        for (int m = 1; m < 16; m <<= 1) rmax = fmaxf(rmax, __shfl_xor(rmax, m, 64));
        float mnew = fmaxf(ml[r], rmax);
        float esc = __expf(ml[r] - mnew);
        float p0 = __expf(v0 - mnew), p1 = __expf(v1 - mnew);
        float p2 = __expf(v2 - mnew), p3 = __expf(v3 - mnew);
        int pr = lhi * 4 + r;
        Pl[w][pr][lrow] = (bf16_t)p0;
        Pl[w][pr][16 + lrow] = (bf16_t)p1;
        Pl[w][pr][32 + lrow] = (bf16_t)p2;
        Pl[w][pr][48 + lrow] = (bf16_t)p3;
        float ps = (p0 + p1) + (p2 + p3);
#pragma unroll
        for (int m = 1; m < 16; m <<= 1) ps += __shfl_xor(ps, m, 64);
        ll[r] = ll[r] * esc + ps;
        ml[r] = mnew;
        if (lrow == 0) Eb[w][1][pr] = esc;
      }
    }

    // ---- rescale accumulators (q = lrow layout) ----
    if (g_act) {
      float escq = Eb[w][0][lrow];
#pragma unroll
      for (int d = 0; d < 8; ++d)
#pragma unroll
        for (int r = 0; r < 4; ++r) og[d][r] *= escq;
    }
    if (l_act) {
      float escq = Eb[w][1][lrow];
#pragma unroll
      for (int d = 0; d < 8; ++d)
#pragma unroll
        for (int r = 0; r < 4; ++r) ol[d][r] *= escq;
    }

    // ---- PV: O^T += V^T * P^T ; V^T A-frags from global, contiguous ----
    bf16x8 pg0, pg1, pl0, pl1;
    if (g_act) {
      pg0 = *(const bf16x8*)(&Pg[w][lrow][lhi * 8]);
      pg1 = *(const bf16x8*)(&Pg[w][lrow][32 + lhi * 8]);
    }
    if (l_act) {
      pl0 = *(const bf16x8*)(&Pl[w][lrow][lhi * 8]);
      pl1 = *(const bf16x8*)(&Pl[w][lrow][32 + lhi * 8]);
    }
#pragma unroll
    for (int d = 0; d < 8; ++d) {
      const bf16_t* vrow = Vt + (size_t)(d * 16 + lrow) * S_LEN + k0 + lhi * 8;
      bf16x8 av0 = *(const bf16x8*)(vrow);
      bf16x8 av1 = *(const bf16x8*)(vrow + 32);
      if (g_act) {
        og[d] = __builtin_amdgcn_mfma_f32_16x16x32_bf16(av0, pg0, og[d], 0, 0, 0);
        og[d] = __builtin_amdgcn_mfma_f32_16x16x32_bf16(av1, pg1, og[d], 0, 0, 0);
      }
      if (l_act) {
        ol[d] = __builtin_amdgcn_mfma_f32_16x16x32_bf16(av0, pl0, ol[d], 0, 0, 0);
        ol[d] = __builtin_amdgcn_mfma_f32_16x16x32_bf16(av1, pl1, ol[d], 0, 0, 0);
      }
    }
  }

  // ---- publish denominators in q-order, gate-combine, write O (bf16) ----
#pragma unroll
  for (int r = 0; r < 4; ++r) {
    if (lrow == 0) {
      Lb[w][0][lhi * 4 + r] = lg[r];
      Lb[w][1][lhi * 4 + r] = ll[r];
    }
  }
  float ig = 1.f / Lb[w][0][lrow];
  float il = 1.f / Lb[w][1][lrow];
  float gv = gates[q0w + lrow];
#pragma unroll
  for (int d = 0; d < 8; ++d) {
    bf16x4v o4;
#pragma unroll
    for (int r = 0; r < 4; ++r)
      o4[r] = (bf16_t)(gv * ol[d][r] * il + (1.f - gv) * og[d][r] * ig);
    *(bf16x4v*)(out + (size_t)(q0w + lrow) * HDIM + h * 128 + d * 16 + lhi * 4) = o4;
  }
}

// ---------------- launch ----------------
extern "C" void kernel_launch(void* const* d_in, const int* in_sizes, int n_in,
                              void* d_out, int out_size, void* d_ws, size_t ws_size,
                              hipStream_t stream) {
  const float* hs  = (const float*)d_in[0];
  const float* Wq  = (const float*)d_in[1];
  const float* Wk  = (const float*)d_in[2];
  const float* Wv  = (const float*)d_in[3];
  const float* Wo  = (const float*)d_in[4];
  const float* gw  = (const float*)d_in[5];
  const float* gb  = (const float*)d_in[6];
  const float* lng = (const float*)d_in[7];
  const float* lnb = (const float*)d_in[8];
  float* out = (float*)d_out;  // reference output dtype is float32

  char* ws = (char*)d_ws;
  bf16_t* hsb   = (bf16_t*)(ws);                    // 2048x2048 bf16 = 8 MB
  bf16_t* wt    = (bf16_t*)(ws + 8388608);          // 3072x2048 bf16 (Wq^T|Wk^T|Wv^T) = 12 MB
  bf16_t* wot   = (bf16_t*)(ws + 20971520);         // 2048x2048 bf16 = 8 MB
  bf16_t* qkv   = (bf16_t*)(ws + 29360128);         // 2048x3072 bf16 = 12 MB
  bf16_t* ao    = (bf16_t*)(ws + 41943040);         // 2048x2048 bf16 = 8 MB
  float*  gates = (float*)(ws + 50331648);          // 2048 fp32 (8 KB)
  bf16_t* vtb   = (bf16_t*)(ws + 50339840);         // V^T [512][2048] bf16 = 2 MB

  cast_bf16_kernel<<<4096, 256, 0, stream>>>(hs, hsb, 1048576);
  transpose_cast_kernel<<<dim3(64, 64), 256, 0, stream>>>(Wq, wt, 2048, 2048);
  transpose_cast_kernel<<<dim3(16, 64), 256, 0, stream>>>(Wk, wt + (size_t)2048 * 2048, 2048, 512);
  transpose_cast_kernel<<<dim3(16, 64), 256, 0, stream>>>(Wv, wt + (size_t)2560 * 2048, 2048, 512);
  transpose_cast_kernel<<<dim3(64, 64), 256, 0, stream>>>(Wo, wot, 2048, 2048);

  ln_gate_kernel<<<2048, 256, 0, stream>>>(hs, gw, gb, lng, lnb, gates);
  reg_loss_kernel<<<1, 256, 0, stream>>>(gates, out + (size_t)4194304);

  // fused QKV projection: [S,2048] x [2048,3072] -> [S,3072] (bf16)
  gemm_bt_kernel<bf16_t><<<dim3(24, 16), 256, 0, stream>>>(hsb, wt, qkv, 2048, 3072, 2048);

  // V^T extraction for the attention PV step
  vtrans_kernel<<<dim3(16, 64), 256, 0, stream>>>(qkv, vtb);

  // attention: 512 blocks = 32 chunk-slots x 16 heads, 4 independent waves each
  attn_kernel<<<dim3(512), 256, 0, stream>>>(qkv, vtb, gates, ao);

  // output projection -> d_out (fp32)
  gemm_bt_kernel<float><<<dim3(16, 16), 256, 0, stream>>>(ao, wot, out, 2048, 2048, 2048);
}

// Round 5
// 247.000 us; speedup vs baseline: 1.5885x; 1.5885x over previous
//
#include <hip/hip_runtime.h>
#include <hip/hip_bf16.h>
#include <math.h>

typedef __bf16 bf16_t;
typedef bf16_t bf16x8 __attribute__((ext_vector_type(8)));
typedef bf16_t bf16x4v __attribute__((ext_vector_type(4)));
typedef float f32x4 __attribute__((ext_vector_type(4)));

#define S_LEN 2048
#define HDIM 2048
#define QKV_LD 3072

// ---------------- cast fp32 -> bf16 (vectorized) ----------------
__global__ __launch_bounds__(256) void cast_bf16_kernel(const float* __restrict__ in,
                                                        bf16_t* __restrict__ out, int n4) {
  int i = blockIdx.x * 256 + threadIdx.x;
  if (i >= n4) return;
  float4 v = ((const float4*)in)[i];
  bf16x4v o;
  o[0] = (bf16_t)v.x; o[1] = (bf16_t)v.y; o[2] = (bf16_t)v.z; o[3] = (bf16_t)v.w;
  ((bf16x4v*)out)[i] = o;
}

// ---------------- transpose + cast: in (K x N) fp32 -> out (N x K) bf16 ----------------
__global__ __launch_bounds__(256) void transpose_cast_kernel(const float* __restrict__ in,
                                                             bf16_t* __restrict__ out,
                                                             int K, int N) {
  __shared__ float tile[32][33];
  int n0 = blockIdx.x * 32, k0 = blockIdx.y * 32;
  int tx = threadIdx.x & 31, ty = threadIdx.x >> 5;
#pragma unroll
  for (int i = 0; i < 4; ++i)
    tile[ty + i * 8][tx] = in[(size_t)(k0 + ty + i * 8) * N + n0 + tx];
  __syncthreads();
#pragma unroll
  for (int i = 0; i < 4; ++i)
    out[(size_t)(n0 + ty + i * 8) * K + k0 + tx] = (bf16_t)tile[tx][ty + i * 8];
}

// ---------------- V^T extraction: VT[v=hk*128+d][s] = qkv[s][2560+v] ----------------
__global__ __launch_bounds__(256) void vtrans_kernel(const bf16_t* __restrict__ qkv,
                                                     bf16_t* __restrict__ vt) {
  __shared__ bf16_t tile[32][33];
  int v0 = blockIdx.x * 32, s0 = blockIdx.y * 32;
  int tx = threadIdx.x & 31, ty = threadIdx.x >> 5;
#pragma unroll
  for (int i = 0; i < 4; ++i)
    tile[ty + i * 8][tx] = qkv[(size_t)(s0 + ty + i * 8) * QKV_LD + 2560 + v0 + tx];
  __syncthreads();
#pragma unroll
  for (int i = 0; i < 4; ++i)
    vt[(size_t)(v0 + ty + i * 8) * S_LEN + s0 + tx] = tile[tx][ty + i * 8];
}

// ---------------- block reduction helper (blockDim == 256) ----------------
__device__ __forceinline__ float block_reduce_256(float v, float* red) {
  int tid = threadIdx.x;
  red[tid] = v;
  __syncthreads();
  for (int off = 128; off > 0; off >>= 1) {
    if (tid < off) red[tid] += red[tid + off];
    __syncthreads();
  }
  float r = red[0];
  __syncthreads();
  return r;
}

// ---------------- LayerNorm + gate (one block per row) ----------------
__global__ __launch_bounds__(256) void ln_gate_kernel(const float* __restrict__ hs,
                                                      const float* __restrict__ gw,
                                                      const float* __restrict__ gb,
                                                      const float* __restrict__ lng,
                                                      const float* __restrict__ lnb,
                                                      float* __restrict__ gates) {
  __shared__ float red[256];
  int row = blockIdx.x;
  const float* x = hs + (size_t)row * HDIM;
  float s = 0.f, ss = 0.f;
  for (int i = threadIdx.x * 4; i < HDIM; i += 1024) {
    float4 v = *(const float4*)(x + i);
    s += v.x + v.y + v.z + v.w;
    ss += v.x * v.x + v.y * v.y + v.z * v.z + v.w * v.w;
  }
  s = block_reduce_256(s, red);
  ss = block_reduce_256(ss, red);
  float mean = s * (1.f / HDIM);
  float var = ss * (1.f / HDIM) - mean * mean;
  float rstd = rsqrtf(var + 1e-5f);
  float dot = 0.f;
  for (int i = threadIdx.x * 4; i < HDIM; i += 1024) {
    float4 v = *(const float4*)(x + i);
    float4 g = *(const float4*)(lng + i);
    float4 b = *(const float4*)(lnb + i);
    float4 w = *(const float4*)(gw + i);
    dot += ((v.x - mean) * rstd * g.x + b.x) * w.x;
    dot += ((v.y - mean) * rstd * g.y + b.y) * w.y;
    dot += ((v.z - mean) * rstd * g.z + b.z) * w.z;
    dot += ((v.w - mean) * rstd * g.w + b.w) * w.w;
  }
  dot = block_reduce_256(dot, red);
  if (threadIdx.x == 0) {
    float gi = dot + gb[0];
    gi = fminf(10.f, fmaxf(-10.f, gi));
    gates[row] = 1.f / (1.f + __expf(-gi));
  }
}

// ---------------- regularization loss (single block) -> fp32 scalar ----------------
__global__ __launch_bounds__(256) void reg_loss_kernel(const float* __restrict__ gates,
                                                       float* __restrict__ out) {
  __shared__ float red[256];
  float sb = 0.f, se = 0.f, sg = 0.f;
  for (int i = threadIdx.x; i < S_LEN; i += 256) {
    float g = gates[i];
    float gc = fminf(1.f - 1e-5f, fmaxf(1e-5f, g));
    sb += g * (1.f - g);
    se += g * logf(gc) + (1.f - g) * logf(1.f - gc);
    sg += g;
  }
  sb = block_reduce_256(sb, red);
  se = block_reduce_256(se, red);
  sg = block_reduce_256(sg, red);
  if (threadIdx.x == 0) {
    const float inv = 1.f / (float)S_LEN;
    float reg = -0.1f * (sb * inv) - 0.01f * (se * inv) + 0.1f * (sg * inv);
    out[0] = reg;
  }
}

// ---------------- bf16 GEMM: C(MxN) = A(MxK) * Bt(NxK)^T, all row-major ----------------
template <typename OutT>
__global__ __launch_bounds__(256) void gemm_bt_kernel(const bf16_t* __restrict__ A,
                                                      const bf16_t* __restrict__ Bt,
                                                      OutT* __restrict__ C,
                                                      int M, int N, int K) {
  __shared__ bf16_t As[128][32];
  __shared__ bf16_t Bs[128][32];
  int tid = threadIdx.x;
  int lane = tid & 63, wave = tid >> 6;
  int wr = wave >> 1, wc = wave & 1;
  int m0 = blockIdx.y * 128, n0 = blockIdx.x * 128;
  int lrow = lane & 15, lhi = lane >> 4;
  f32x4 acc[4][4];
#pragma unroll
  for (int a = 0; a < 4; ++a)
#pragma unroll
    for (int b = 0; b < 4; ++b)
#pragma unroll
      for (int r = 0; r < 4; ++r) acc[a][b][r] = 0.f;

  for (int k0 = 0; k0 < K; k0 += 32) {
    __syncthreads();
#pragma unroll
    for (int i = 0; i < 2; ++i) {
      int c = tid * 2 + i;
      int rr = c >> 2, kk = (c & 3) * 8;
      *(uint4*)(&As[rr][kk]) = *(const uint4*)(A + (size_t)(m0 + rr) * K + k0 + kk);
      *(uint4*)(&Bs[rr][kk]) = *(const uint4*)(Bt + (size_t)(n0 + rr) * K + k0 + kk);
    }
    __syncthreads();
    bf16x8 af[4], bfr[4];
#pragma unroll
    for (int a = 0; a < 4; ++a)
      af[a] = *(const bf16x8*)(&As[wr * 64 + a * 16 + lrow][lhi * 8]);
#pragma unroll
    for (int b = 0; b < 4; ++b)
      bfr[b] = *(const bf16x8*)(&Bs[wc * 64 + b * 16 + lrow][lhi * 8]);
#pragma unroll
    for (int a = 0; a < 4; ++a)
#pragma unroll
      for (int b = 0; b < 4; ++b)
        acc[a][b] = __builtin_amdgcn_mfma_f32_16x16x32_bf16(af[a], bfr[b], acc[a][b], 0, 0, 0);
  }
#pragma unroll
  for (int a = 0; a < 4; ++a)
#pragma unroll
    for (int b = 0; b < 4; ++b)
#pragma unroll
      for (int r = 0; r < 4; ++r) {
        int row = m0 + wr * 64 + a * 16 + lhi * 4 + r;
        int col = n0 + wc * 64 + b * 16 + lrow;
        C[(size_t)row * N + col] = (OutT)acc[a][b][r];
      }
}

// ---------------- dual-softmax flash attention v5 ----------------
// v2 structure (LDS-staged K + V^T, reg-staged double buffer, 1 barrier/tile)
// with v3's precomputed global V^T feeding LINEAR coalesced LDS staging.
// All LDS accesses XOR-chunk-swizzled -> balanced 8 lanes per 16B chunk-group
// (= the wave64 b128 minimum), no transpose writes, no scattered global gathers.
__global__ __launch_bounds__(256, 2) void attn_kernel(const bf16_t* __restrict__ QKV,
                                                      const bf16_t* __restrict__ VTg,
                                                      const float* __restrict__ gates,
                                                      bf16_t* __restrict__ out) {
  __shared__ bf16_t Ks[2][64][128];   // 32 KB, 16B-chunk swizzle: c ^= row&7
  __shared__ bf16_t Vt[2][128][64];   // 32 KB, V^T tile, same swizzle
  __shared__ bf16_t Pw[4][16][72];    // 9 KB, per-wave P (g then l, sequential)

  int b = blockIdx.x;
  int h = b & 15;
  int t5 = b >> 4;
  int c = (t5 < 16) ? (31 - t5) : (t5 - 16);  // pair c with 31-c for load balance
  int q0c = c * 64;
  int tid = threadIdx.x;
  int lane = tid & 63, w = tid >> 6;
  int lrow = lane & 15, lhi = lane >> 4;
  int q0w = q0c + w * 16;
  int hk = h & 3;
  const bf16_t* Qp = QKV + h * 128;
  const bf16_t* Kp = QKV + 2048 + hk * 128;
  const bf16_t* Vt_g = VTg + (size_t)hk * 128 * S_LEN;

  // Q A-fragments: lane holds Q[q0w+lrow][ks*32 + lhi*8 ..+8]
  bf16x8 aq[4];
#pragma unroll
  for (int ks = 0; ks < 4; ++ks)
    aq[ks] = *(const bf16x8*)(Qp + (size_t)(q0w + lrow) * QKV_LD + ks * 32 + lhi * 8);

  float mg[4], ml[4], lg[4], ll[4];
  f32x4 og[8], ol[8];  // C row = q (lhi*4+r), col = d*16+lrow
#pragma unroll
  for (int r = 0; r < 4; ++r) { mg[r] = ml[r] = -1e30f; lg[r] = ll[r] = 0.f; }
#pragma unroll
  for (int d = 0; d < 8; ++d)
#pragma unroll
    for (int r = 0; r < 4; ++r) { og[d][r] = 0.f; ol[d][r] = 0.f; }

  const float NEGINF = -__builtin_inff();
  const float scl = 0.08838834764831845f;  // 1/sqrt(128)
  int kend = q0c + 128;
  if (kend > S_LEN) kend = S_LEN;
  int nt = kend >> 6;

  // staging thread mapping
  int kr = tid >> 4, c16 = tid & 15;   // K: rows kr+16i, 16B chunk c16 (of 16)
  int vr = tid >> 3, c8 = tid & 7;     // VT: rows vr+32i, 16B chunk c8 (of 8)

  // ---- prologue: stage tile 0 into buffer 0 ----
  {
    bf16x8 kreg[4], vreg[4];
#pragma unroll
    for (int i = 0; i < 4; ++i)
      kreg[i] = *(const bf16x8*)(Kp + (size_t)(kr + i * 16) * QKV_LD + c16 * 8);
#pragma unroll
    for (int i = 0; i < 4; ++i)
      vreg[i] = *(const bf16x8*)(Vt_g + (size_t)(vr + i * 32) * S_LEN + c8 * 8);
#pragma unroll
    for (int i = 0; i < 4; ++i) {
      int rr = kr + i * 16;
      *(bf16x8*)(&Ks[0][rr][(c16 ^ (rr & 7)) * 8]) = kreg[i];
    }
#pragma unroll
    for (int i = 0; i < 4; ++i) {
      int rr = vr + i * 32;
      *(bf16x8*)(&Vt[0][rr][(c8 ^ (rr & 7)) * 8]) = vreg[i];
    }
  }
  __syncthreads();

  for (int ti = 0; ti < nt; ++ti) {
    int k0 = ti << 6;
    int bufc = ti & 1, bufn = bufc ^ 1;
    bool more = (ti + 1 < nt);

    // ---- issue next tile's global loads early (hide under compute) ----
    bf16x8 kreg[4], vreg[4];
    if (more) {
      int k0n = k0 + 64;
#pragma unroll
      for (int i = 0; i < 4; ++i)
        kreg[i] = *(const bf16x8*)(Kp + (size_t)(k0n + kr + i * 16) * QKV_LD + c16 * 8);
#pragma unroll
      for (int i = 0; i < 4; ++i)
        vreg[i] = *(const bf16x8*)(Vt_g + (size_t)(vr + i * 32) * S_LEN + k0n + c8 * 8);
    }

    // ---- QK^T: 16q x 64k per wave, K B-frags from LDS (swizzled) ----
    f32x4 sc[4];
#pragma unroll
    for (int t = 0; t < 4; ++t) {
#pragma unroll
      for (int r = 0; r < 4; ++r) sc[t][r] = 0.f;
    }
#pragma unroll
    for (int t = 0; t < 4; ++t) {
      int n = t * 16 + lrow;
      int swz = n & 7;
#pragma unroll
      for (int ks = 0; ks < 4; ++ks) {
        bf16x8 bk = *(const bf16x8*)(&Ks[bufc][n][((ks * 4 + lhi) ^ swz) * 8]);
        sc[t] = __builtin_amdgcn_mfma_f32_16x16x32_bf16(aq[ks], bk, sc[t], 0, 0, 0);
      }
    }

    bool g_act = (k0 <= q0w + 15);
    bool g_full = (k0 + 63 <= q0w);
    bool l_act = (k0 + 63 >= q0w - 64) && (k0 <= q0w + 79);

    // ---- global (causal) branch ----
    if (g_act) {
#pragma unroll
      for (int r = 0; r < 4; ++r) {
        int i = q0w + lhi * 4 + r;
        float v0, v1, v2, v3;
        if (g_full) {
          v0 = sc[0][r] * scl; v1 = sc[1][r] * scl;
          v2 = sc[2][r] * scl; v3 = sc[3][r] * scl;
        } else {
          int j = k0 + lrow;
          v0 = (j > i) ? NEGINF : sc[0][r] * scl;
          v1 = (j + 16 > i) ? NEGINF : sc[1][r] * scl;
          v2 = (j + 32 > i) ? NEGINF : sc[2][r] * scl;
          v3 = (j + 48 > i) ? NEGINF : sc[3][r] * scl;
        }
        float rmax = fmaxf(fmaxf(v0, v1), fmaxf(v2, v3));
#pragma unroll
        for (int m = 1; m < 16; m <<= 1) rmax = fmaxf(rmax, __shfl_xor(rmax, m, 64));
        float mnew = fmaxf(mg[r], rmax);
        float esc = __expf(mg[r] - mnew);
        float p0 = __expf(v0 - mnew), p1 = __expf(v1 - mnew);
        float p2 = __expf(v2 - mnew), p3 = __expf(v3 - mnew);
        int pr = lhi * 4 + r;
        Pw[w][pr][lrow] = (bf16_t)p0;
        Pw[w][pr][16 + lrow] = (bf16_t)p1;
        Pw[w][pr][32 + lrow] = (bf16_t)p2;
        Pw[w][pr][48 + lrow] = (bf16_t)p3;
        float ps = (p0 + p1) + (p2 + p3);
#pragma unroll
        for (int m = 1; m < 16; m <<= 1) ps += __shfl_xor(ps, m, 64);
        lg[r] = lg[r] * esc + ps;
        mg[r] = mnew;
#pragma unroll
        for (int d = 0; d < 8; ++d) og[d][r] *= esc;
      }
      bf16x8 ap0 = *(const bf16x8*)(&Pw[w][lrow][lhi * 8]);
      bf16x8 ap1 = *(const bf16x8*)(&Pw[w][lrow][32 + lhi * 8]);
#pragma unroll
      for (int d = 0; d < 8; ++d) {
        int drow = d * 16 + lrow;
        int swz = drow & 7;
        bf16x8 bv0 = *(const bf16x8*)(&Vt[bufc][drow][(lhi ^ swz) * 8]);
        bf16x8 bv1 = *(const bf16x8*)(&Vt[bufc][drow][((4 + lhi) ^ swz) * 8]);
        og[d] = __builtin_amdgcn_mfma_f32_16x16x32_bf16(ap0, bv0, og[d], 0, 0, 0);
        og[d] = __builtin_amdgcn_mfma_f32_16x16x32_bf16(ap1, bv1, og[d], 0, 0, 0);
      }
    }

    // ---- local (band) branch: only ~3 tiles per wave ----
    if (l_act) {
#pragma unroll
      for (int r = 0; r < 4; ++r) {
        int i = q0w + lhi * 4 + r;
        int j = k0 + lrow;
        int d0 = i - j, d1 = d0 - 16, d2 = d0 - 32, d3 = d0 - 48;
        float v0 = (d0 > 64 || d0 < -64) ? NEGINF : sc[0][r] * scl;
        float v1 = (d1 > 64 || d1 < -64) ? NEGINF : sc[1][r] * scl;
        float v2 = (d2 > 64 || d2 < -64) ? NEGINF : sc[2][r] * scl;
        float v3 = (d3 > 64 || d3 < -64) ? NEGINF : sc[3][r] * scl;
        float rmax = fmaxf(fmaxf(v0, v1), fmaxf(v2, v3));
#pragma unroll
        for (int m = 1; m < 16; m <<= 1) rmax = fmaxf(rmax, __shfl_xor(rmax, m, 64));
        float mnew = fmaxf(ml[r], rmax);
        float esc = __expf(ml[r] - mnew);
        float p0 = __expf(v0 - mnew), p1 = __expf(v1 - mnew);
        float p2 = __expf(v2 - mnew), p3 = __expf(v3 - mnew);
        int pr = lhi * 4 + r;
        Pw[w][pr][lrow] = (bf16_t)p0;
        Pw[w][pr][16 + lrow] = (bf16_t)p1;
        Pw[w][pr][32 + lrow] = (bf16_t)p2;
        Pw[w][pr][48 + lrow] = (bf16_t)p3;
        float ps = (p0 + p1) + (p2 + p3);
#pragma unroll
        for (int m = 1; m < 16; m <<= 1) ps += __shfl_xor(ps, m, 64);
        ll[r] = ll[r] * esc + ps;
        ml[r] = mnew;
#pragma unroll
        for (int d = 0; d < 8; ++d) ol[d][r] *= esc;
      }
      bf16x8 ap0 = *(const bf16x8*)(&Pw[w][lrow][lhi * 8]);
      bf16x8 ap1 = *(const bf16x8*)(&Pw[w][lrow][32 + lhi * 8]);
#pragma unroll
      for (int d = 0; d < 8; ++d) {
        int drow = d * 16 + lrow;
        int swz = drow & 7;
        bf16x8 bv0 = *(const bf16x8*)(&Vt[bufc][drow][(lhi ^ swz) * 8]);
        bf16x8 bv1 = *(const bf16x8*)(&Vt[bufc][drow][((4 + lhi) ^ swz) * 8]);
        ol[d] = __builtin_amdgcn_mfma_f32_16x16x32_bf16(ap0, bv0, ol[d], 0, 0, 0);
        ol[d] = __builtin_amdgcn_mfma_f32_16x16x32_bf16(ap1, bv1, ol[d], 0, 0, 0);
      }
    }

    // ---- write next tile into the other buffer, then fence ----
    if (more) {
#pragma unroll
      for (int i = 0; i < 4; ++i) {
        int rr = kr + i * 16;
        *(bf16x8*)(&Ks[bufn][rr][(c16 ^ (rr & 7)) * 8]) = kreg[i];
      }
#pragma unroll
      for (int i = 0; i < 4; ++i) {
        int rr = vr + i * 32;
        *(bf16x8*)(&Vt[bufn][rr][(c8 ^ (rr & 7)) * 8]) = vreg[i];
      }
    }
    __syncthreads();
  }

  // ---- gate-combine and write attn_out (bf16, [S][2048]) ----
#pragma unroll
  for (int r = 0; r < 4; ++r) {
    int i = q0w + lhi * 4 + r;
    float gv = gates[i];
    float il = 1.f / ll[r], ig = 1.f / lg[r];
#pragma unroll
    for (int d = 0; d < 8; ++d)
      out[(size_t)i * HDIM + h * 128 + d * 16 + lrow] =
          (bf16_t)(gv * ol[d][r] * il + (1.f - gv) * og[d][r] * ig);
  }
}

// ---------------- launch ----------------
extern "C" void kernel_launch(void* const* d_in, const int* in_sizes, int n_in,
                              void* d_out, int out_size, void* d_ws, size_t ws_size,
                              hipStream_t stream) {
  const float* hs  = (const float*)d_in[0];
  const float* Wq  = (const float*)d_in[1];
  const float* Wk  = (const float*)d_in[2];
  const float* Wv  = (const float*)d_in[3];
  const float* Wo  = (const float*)d_in[4];
  const float* gw  = (const float*)d_in[5];
  const float* gb  = (const float*)d_in[6];
  const float* lng = (const float*)d_in[7];
  const float* lnb = (const float*)d_in[8];
  float* out = (float*)d_out;  // reference output dtype is float32

  char* ws = (char*)d_ws;
  bf16_t* hsb   = (bf16_t*)(ws);                    // 2048x2048 bf16 = 8 MB
  bf16_t* wt    = (bf16_t*)(ws + 8388608);          // 3072x2048 bf16 (Wq^T|Wk^T|Wv^T) = 12 MB
  bf16_t* wot   = (bf16_t*)(ws + 20971520);         // 2048x2048 bf16 = 8 MB
  bf16_t* qkv   = (bf16_t*)(ws + 29360128);         // 2048x3072 bf16 = 12 MB
  bf16_t* ao    = (bf16_t*)(ws + 41943040);         // 2048x2048 bf16 = 8 MB
  float*  gates = (float*)(ws + 50331648);          // 2048 fp32 (8 KB)
  bf16_t* vtb   = (bf16_t*)(ws + 50339840);         // V^T [512][2048] bf16 = 2 MB

  cast_bf16_kernel<<<4096, 256, 0, stream>>>(hs, hsb, 1048576);
  transpose_cast_kernel<<<dim3(64, 64), 256, 0, stream>>>(Wq, wt, 2048, 2048);
  transpose_cast_kernel<<<dim3(16, 64), 256, 0, stream>>>(Wk, wt + (size_t)2048 * 2048, 2048, 512);
  transpose_cast_kernel<<<dim3(16, 64), 256, 0, stream>>>(Wv, wt + (size_t)2560 * 2048, 2048, 512);
  transpose_cast_kernel<<<dim3(64, 64), 256, 0, stream>>>(Wo, wot, 2048, 2048);

  ln_gate_kernel<<<2048, 256, 0, stream>>>(hs, gw, gb, lng, lnb, gates);
  reg_loss_kernel<<<1, 256, 0, stream>>>(gates, out + (size_t)4194304);

  // fused QKV projection: [S,2048] x [2048,3072] -> [S,3072] (bf16)
  gemm_bt_kernel<bf16_t><<<dim3(24, 16), 256, 0, stream>>>(hsb, wt, qkv, 2048, 3072, 2048);

  // V^T extraction for the attention PV step
  vtrans_kernel<<<dim3(16, 64), 256, 0, stream>>>(qkv, vtb);

  // attention: 512 blocks = 32 chunk-slots x 16 heads, 4 waves each
  attn_kernel<<<dim3(512), 256, 0, stream>>>(qkv, vtb, gates, ao);

  // output projection -> d_out (fp32)
  gemm_bt_kernel<float><<<dim3(16, 16), 256, 0, stream>>>(ao, wot, out, 2048, 2048, 2048);
}

// Round 6
// 226.292 us; speedup vs baseline: 1.7339x; 1.0915x over previous
//
#include <hip/hip_runtime.h>
#include <hip/hip_bf16.h>
#include <math.h>

typedef __bf16 bf16_t;
typedef bf16_t bf16x8 __attribute__((ext_vector_type(8)));
typedef bf16_t bf16x4v __attribute__((ext_vector_type(4)));
typedef float f32x4 __attribute__((ext_vector_type(4)));

#define S_LEN 2048
#define HDIM 2048
#define QKV_LD 3072

// async global->LDS, 16B per lane. LDS dest is wave-uniform base + lane*16.
__device__ __forceinline__ void gload_lds16(const bf16_t* g, bf16_t* l) {
  __builtin_amdgcn_global_load_lds(
      (const __attribute__((address_space(1))) unsigned int*)g,
      (__attribute__((address_space(3))) unsigned int*)l, 16, 0, 0);
}

// ---------------- fused LayerNorm + gate + bf16 cast (one block per row) ----------------
__global__ __launch_bounds__(256) void ln_gate_cast_kernel(const float* __restrict__ hs,
                                                           const float* __restrict__ gw,
                                                           const float* __restrict__ gb,
                                                           const float* __restrict__ lng,
                                                           const float* __restrict__ lnb,
                                                           float* __restrict__ gates,
                                                           bf16_t* __restrict__ hsb) {
  __shared__ float red[256];
  int row = blockIdx.x, tid = threadIdx.x;
  const float* x = hs + (size_t)row * HDIM;
  bf16_t* y = hsb + (size_t)row * HDIM;
  float4 v0 = ((const float4*)x)[tid];
  float4 v1 = ((const float4*)x)[tid + 256];
  bf16x4v o;
  o[0] = (bf16_t)v0.x; o[1] = (bf16_t)v0.y; o[2] = (bf16_t)v0.z; o[3] = (bf16_t)v0.w;
  ((bf16x4v*)y)[tid] = o;
  o[0] = (bf16_t)v1.x; o[1] = (bf16_t)v1.y; o[2] = (bf16_t)v1.z; o[3] = (bf16_t)v1.w;
  ((bf16x4v*)y)[tid + 256] = o;
  float s = v0.x + v0.y + v0.z + v0.w + v1.x + v1.y + v1.z + v1.w;
  float ss = v0.x * v0.x + v0.y * v0.y + v0.z * v0.z + v0.w * v0.w +
             v1.x * v1.x + v1.y * v1.y + v1.z * v1.z + v1.w * v1.w;
  // block reduce
  red[tid] = s; __syncthreads();
  for (int off = 128; off > 0; off >>= 1) { if (tid < off) red[tid] += red[tid + off]; __syncthreads(); }
  s = red[0]; __syncthreads();
  red[tid] = ss; __syncthreads();
  for (int off = 128; off > 0; off >>= 1) { if (tid < off) red[tid] += red[tid + off]; __syncthreads(); }
  ss = red[0]; __syncthreads();
  float mean = s * (1.f / HDIM);
  float var = ss * (1.f / HDIM) - mean * mean;
  float rstd = rsqrtf(var + 1e-5f);
  float dot = 0.f;
#pragma unroll
  for (int half = 0; half < 2; ++half) {
    int i = tid * 4 + half * 1024;
    float4 v = half ? v1 : v0;
    float4 g = *(const float4*)(lng + i);
    float4 b = *(const float4*)(lnb + i);
    float4 w = *(const float4*)(gw + i);
    dot += ((v.x - mean) * rstd * g.x + b.x) * w.x;
    dot += ((v.y - mean) * rstd * g.y + b.y) * w.y;
    dot += ((v.z - mean) * rstd * g.z + b.z) * w.z;
    dot += ((v.w - mean) * rstd * g.w + b.w) * w.w;
  }
  red[tid] = dot; __syncthreads();
  for (int off = 128; off > 0; off >>= 1) { if (tid < off) red[tid] += red[tid + off]; __syncthreads(); }
  if (tid == 0) {
    float gi = red[0] + gb[0];
    gi = fminf(10.f, fmaxf(-10.f, gi));
    gates[row] = 1.f / (1.f + __expf(-gi));
  }
}

// ---------------- merged Wq/Wk/Wv transpose+cast -> wt (N x K layout) ----------------
__global__ __launch_bounds__(256) void wqkv_trans_kernel(const float* __restrict__ Wq,
                                                         const float* __restrict__ Wk,
                                                         const float* __restrict__ Wv,
                                                         bf16_t* __restrict__ wt) {
  __shared__ float tile[32][33];
  int bx = blockIdx.x, k0 = blockIdx.y * 32;
  const float* src; int N, n0, o0;
  if (bx < 64)      { src = Wq; N = 2048; n0 = bx * 32;        o0 = n0; }
  else if (bx < 80) { src = Wk; N = 512;  n0 = (bx - 64) * 32; o0 = 2048 + n0; }
  else              { src = Wv; N = 512;  n0 = (bx - 80) * 32; o0 = 2560 + n0; }
  int tx = threadIdx.x & 31, ty = threadIdx.x >> 5;
#pragma unroll
  for (int i = 0; i < 4; ++i)
    tile[ty + i * 8][tx] = src[(size_t)(k0 + ty + i * 8) * N + n0 + tx];
  __syncthreads();
#pragma unroll
  for (int i = 0; i < 4; ++i)
    wt[(size_t)(o0 + ty + i * 8) * 2048 + k0 + tx] = (bf16_t)tile[tx][ty + i * 8];
}

// ---------------- transpose + cast: in (K x N) fp32 -> out (N x K) bf16 (Wo) ----------------
__global__ __launch_bounds__(256) void transpose_cast_kernel(const float* __restrict__ in,
                                                             bf16_t* __restrict__ out,
                                                             int K, int N) {
  __shared__ float tile[32][33];
  int n0 = blockIdx.x * 32, k0 = blockIdx.y * 32;
  int tx = threadIdx.x & 31, ty = threadIdx.x >> 5;
#pragma unroll
  for (int i = 0; i < 4; ++i)
    tile[ty + i * 8][tx] = in[(size_t)(k0 + ty + i * 8) * N + n0 + tx];
  __syncthreads();
#pragma unroll
  for (int i = 0; i < 4; ++i)
    out[(size_t)(n0 + ty + i * 8) * K + k0 + tx] = (bf16_t)tile[tx][ty + i * 8];
}

// ---------------- V^T extraction: VT[v=hk*128+d][s] = qkv[s][2560+v] ----------------
__global__ __launch_bounds__(256) void vtrans_kernel(const bf16_t* __restrict__ qkv,
                                                     bf16_t* __restrict__ vt) {
  __shared__ bf16_t tile[32][33];
  int v0 = blockIdx.x * 32, s0 = blockIdx.y * 32;
  int tx = threadIdx.x & 31, ty = threadIdx.x >> 5;
#pragma unroll
  for (int i = 0; i < 4; ++i)
    tile[ty + i * 8][tx] = qkv[(size_t)(s0 + ty + i * 8) * QKV_LD + 2560 + v0 + tx];
  __syncthreads();
#pragma unroll
  for (int i = 0; i < 4; ++i)
    vt[(size_t)(v0 + ty + i * 8) * S_LEN + s0 + tx] = tile[tx][ty + i * 8];
}

// ---------------- regularization loss (single block) -> fp32 scalar ----------------
__global__ __launch_bounds__(256) void reg_loss_kernel(const float* __restrict__ gates,
                                                       float* __restrict__ out) {
  __shared__ float red[256];
  int tid = threadIdx.x;
  float sb = 0.f, se = 0.f, sg = 0.f;
  for (int i = tid; i < S_LEN; i += 256) {
    float g = gates[i];
    float gc = fminf(1.f - 1e-5f, fmaxf(1e-5f, g));
    sb += g * (1.f - g);
    se += g * logf(gc) + (1.f - g) * logf(1.f - gc);
    sg += g;
  }
  red[tid] = sb; __syncthreads();
  for (int off = 128; off > 0; off >>= 1) { if (tid < off) red[tid] += red[tid + off]; __syncthreads(); }
  sb = red[0]; __syncthreads();
  red[tid] = se; __syncthreads();
  for (int off = 128; off > 0; off >>= 1) { if (tid < off) red[tid] += red[tid + off]; __syncthreads(); }
  se = red[0]; __syncthreads();
  red[tid] = sg; __syncthreads();
  for (int off = 128; off > 0; off >>= 1) { if (tid < off) red[tid] += red[tid + off]; __syncthreads(); }
  if (tid == 0) {
    const float inv = 1.f / (float)S_LEN;
    float reg = -0.1f * (sb * inv) - 0.01f * (se * inv) + 0.1f * (red[0] * inv);
    out[0] = reg;
  }
}

// ---------------- bf16 GEMM: C(MxN) = A(MxK) * Bt(NxK)^T, global_load_lds staging ----------------
// m97 structure: 128x128 tile, BK=32, 4 waves, 16x16x32 MFMA, async width-16 staging.
template <typename OutT>
__global__ __launch_bounds__(256) void gemm_bt_kernel(const bf16_t* __restrict__ A,
                                                      const bf16_t* __restrict__ Bt,
                                                      OutT* __restrict__ C,
                                                      int M, int N, int K) {
  __shared__ bf16_t As[128][32];
  __shared__ bf16_t Bs[128][32];
  int tid = threadIdx.x;
  int lane = tid & 63, wave = tid >> 6;
  int wr = wave >> 1, wc = wave & 1;
  int m0 = blockIdx.y * 128, n0 = blockIdx.x * 128;
  int lrow = lane & 15, lhi = lane >> 4;

  // staging: wave covers 32 rows (2 insts x 16 rows); lane -> row base+lane/4, 16B chunk lane%4
  int srow = wave * 32 + (lane >> 2);
  int scol = (lane & 3) * 8;
  const bf16_t* Ag = A + (size_t)(m0 + srow) * K + scol;
  const bf16_t* Bg = Bt + (size_t)(n0 + srow) * K + scol;
  size_t row16 = (size_t)16 * K;
  bf16_t* As0 = &As[wave * 32][0];
  bf16_t* As1 = &As[wave * 32 + 16][0];
  bf16_t* Bs0 = &Bs[wave * 32][0];
  bf16_t* Bs1 = &Bs[wave * 32 + 16][0];

  f32x4 acc[4][4];
#pragma unroll
  for (int a = 0; a < 4; ++a)
#pragma unroll
    for (int b = 0; b < 4; ++b)
#pragma unroll
      for (int r = 0; r < 4; ++r) acc[a][b][r] = 0.f;

  for (int k0 = 0; k0 < K; k0 += 32) {
    __syncthreads();
    gload_lds16(Ag + k0, As0);
    gload_lds16(Ag + k0 + row16, As1);
    gload_lds16(Bg + k0, Bs0);
    gload_lds16(Bg + k0 + row16, Bs1);
    __syncthreads();  // vmcnt(0) drained by compiler before barrier
    bf16x8 af[4], bfr[4];
#pragma unroll
    for (int a = 0; a < 4; ++a)
      af[a] = *(const bf16x8*)(&As[wr * 64 + a * 16 + lrow][lhi * 8]);
#pragma unroll
    for (int b = 0; b < 4; ++b)
      bfr[b] = *(const bf16x8*)(&Bs[wc * 64 + b * 16 + lrow][lhi * 8]);
    __builtin_amdgcn_s_setprio(1);
#pragma unroll
    for (int a = 0; a < 4; ++a)
#pragma unroll
      for (int b = 0; b < 4; ++b)
        acc[a][b] = __builtin_amdgcn_mfma_f32_16x16x32_bf16(af[a], bfr[b], acc[a][b], 0, 0, 0);
    __builtin_amdgcn_s_setprio(0);
  }
#pragma unroll
  for (int a = 0; a < 4; ++a)
#pragma unroll
    for (int b = 0; b < 4; ++b)
#pragma unroll
      for (int r = 0; r < 4; ++r) {
        int row = m0 + wr * 64 + a * 16 + lhi * 4 + r;
        int col = n0 + wc * 64 + b * 16 + lrow;
        C[(size_t)row * N + col] = (OutT)acc[a][b][r];
      }
}

// ---------------- dual-softmax flash attention v5 (+setprio) ----------------
__global__ __launch_bounds__(256, 2) void attn_kernel(const bf16_t* __restrict__ QKV,
                                                      const bf16_t* __restrict__ VTg,
                                                      const float* __restrict__ gates,
                                                      bf16_t* __restrict__ out) {
  __shared__ bf16_t Ks[2][64][128];   // 32 KB, 16B-chunk swizzle: c ^= row&7
  __shared__ bf16_t Vt[2][128][64];   // 32 KB, V^T tile, same swizzle
  __shared__ bf16_t Pw[4][16][72];    // 9 KB, per-wave P (g then l, sequential)

  int b = blockIdx.x;
  int h = b & 15;
  int t5 = b >> 4;
  int c = (t5 < 16) ? (31 - t5) : (t5 - 16);  // pair c with 31-c for load balance
  int q0c = c * 64;
  int tid = threadIdx.x;
  int lane = tid & 63, w = tid >> 6;
  int lrow = lane & 15, lhi = lane >> 4;
  int q0w = q0c + w * 16;
  int hk = h & 3;
  const bf16_t* Qp = QKV + h * 128;
  const bf16_t* Kp = QKV + 2048 + hk * 128;
  const bf16_t* Vt_g = VTg + (size_t)hk * 128 * S_LEN;

  bf16x8 aq[4];
#pragma unroll
  for (int ks = 0; ks < 4; ++ks)
    aq[ks] = *(const bf16x8*)(Qp + (size_t)(q0w + lrow) * QKV_LD + ks * 32 + lhi * 8);

  float mg[4], ml[4], lg[4], ll[4];
  f32x4 og[8], ol[8];
#pragma unroll
  for (int r = 0; r < 4; ++r) { mg[r] = ml[r] = -1e30f; lg[r] = ll[r] = 0.f; }
#pragma unroll
  for (int d = 0; d < 8; ++d)
#pragma unroll
    for (int r = 0; r < 4; ++r) { og[d][r] = 0.f; ol[d][r] = 0.f; }

  const float NEGINF = -__builtin_inff();
  const float scl = 0.08838834764831845f;  // 1/sqrt(128)
  int kend = q0c + 128;
  if (kend > S_LEN) kend = S_LEN;
  int nt = kend >> 6;

  int kr = tid >> 4, c16 = tid & 15;
  int vr = tid >> 3, c8 = tid & 7;

  {
    bf16x8 kreg[4], vreg[4];
#pragma unroll
    for (int i = 0; i < 4; ++i)
      kreg[i] = *(const bf16x8*)(Kp + (size_t)(kr + i * 16) * QKV_LD + c16 * 8);
#pragma unroll
    for (int i = 0; i < 4; ++i)
      vreg[i] = *(const bf16x8*)(Vt_g + (size_t)(vr + i * 32) * S_LEN + c8 * 8);
#pragma unroll
    for (int i = 0; i < 4; ++i) {
      int rr = kr + i * 16;
      *(bf16x8*)(&Ks[0][rr][(c16 ^ (rr & 7)) * 8]) = kreg[i];
    }
#pragma unroll
    for (int i = 0; i < 4; ++i) {
      int rr = vr + i * 32;
      *(bf16x8*)(&Vt[0][rr][(c8 ^ (rr & 7)) * 8]) = vreg[i];
    }
  }
  __syncthreads();

  for (int ti = 0; ti < nt; ++ti) {
    int k0 = ti << 6;
    int bufc = ti & 1, bufn = bufc ^ 1;
    bool more = (ti + 1 < nt);

    bf16x8 kreg[4], vreg[4];
    if (more) {
      int k0n = k0 + 64;
#pragma unroll
      for (int i = 0; i < 4; ++i)
        kreg[i] = *(const bf16x8*)(Kp + (size_t)(k0n + kr + i * 16) * QKV_LD + c16 * 8);
#pragma unroll
      for (int i = 0; i < 4; ++i)
        vreg[i] = *(const bf16x8*)(Vt_g + (size_t)(vr + i * 32) * S_LEN + k0n + c8 * 8);
    }

    f32x4 sc[4];
#pragma unroll
    for (int t = 0; t < 4; ++t) {
#pragma unroll
      for (int r = 0; r < 4; ++r) sc[t][r] = 0.f;
    }
    __builtin_amdgcn_s_setprio(1);
#pragma unroll
    for (int t = 0; t < 4; ++t) {
      int n = t * 16 + lrow;
      int swz = n & 7;
#pragma unroll
      for (int ks = 0; ks < 4; ++ks) {
        bf16x8 bk = *(const bf16x8*)(&Ks[bufc][n][((ks * 4 + lhi) ^ swz) * 8]);
        sc[t] = __builtin_amdgcn_mfma_f32_16x16x32_bf16(aq[ks], bk, sc[t], 0, 0, 0);
      }
    }
    __builtin_amdgcn_s_setprio(0);

    bool g_act = (k0 <= q0w + 15);
    bool g_full = (k0 + 63 <= q0w);
    bool l_act = (k0 + 63 >= q0w - 64) && (k0 <= q0w + 79);

    if (g_act) {
#pragma unroll
      for (int r = 0; r < 4; ++r) {
        int i = q0w + lhi * 4 + r;
        float v0, v1, v2, v3;
        if (g_full) {
          v0 = sc[0][r] * scl; v1 = sc[1][r] * scl;
          v2 = sc[2][r] * scl; v3 = sc[3][r] * scl;
        } else {
          int j = k0 + lrow;
          v0 = (j > i) ? NEGINF : sc[0][r] * scl;
          v1 = (j + 16 > i) ? NEGINF : sc[1][r] * scl;
          v2 = (j + 32 > i) ? NEGINF : sc[2][r] * scl;
          v3 = (j + 48 > i) ? NEGINF : sc[3][r] * scl;
        }
        float rmax = fmaxf(fmaxf(v0, v1), fmaxf(v2, v3));
#pragma unroll
        for (int m = 1; m < 16; m <<= 1) rmax = fmaxf(rmax, __shfl_xor(rmax, m, 64));
        float mnew = fmaxf(mg[r], rmax);
        float esc = __expf(mg[r] - mnew);
        float p0 = __expf(v0 - mnew), p1 = __expf(v1 - mnew);
        float p2 = __expf(v2 - mnew), p3 = __expf(v3 - mnew);
        int pr = lhi * 4 + r;
        Pw[w][pr][lrow] = (bf16_t)p0;
        Pw[w][pr][16 + lrow] = (bf16_t)p1;
        Pw[w][pr][32 + lrow] = (bf16_t)p2;
        Pw[w][pr][48 + lrow] = (bf16_t)p3;
        float ps = (p0 + p1) + (p2 + p3);
#pragma unroll
        for (int m = 1; m < 16; m <<= 1) ps += __shfl_xor(ps, m, 64);
        lg[r] = lg[r] * esc + ps;
        mg[r] = mnew;
#pragma unroll
        for (int d = 0; d < 8; ++d) og[d][r] *= esc;
      }
      bf16x8 ap0 = *(const bf16x8*)(&Pw[w][lrow][lhi * 8]);
      bf16x8 ap1 = *(const bf16x8*)(&Pw[w][lrow][32 + lhi * 8]);
      __builtin_amdgcn_s_setprio(1);
#pragma unroll
      for (int d = 0; d < 8; ++d) {
        int drow = d * 16 + lrow;
        int swz = drow & 7;
        bf16x8 bv0 = *(const bf16x8*)(&Vt[bufc][drow][(lhi ^ swz) * 8]);
        bf16x8 bv1 = *(const bf16x8*)(&Vt[bufc][drow][((4 + lhi) ^ swz) * 8]);
        og[d] = __builtin_amdgcn_mfma_f32_16x16x32_bf16(ap0, bv0, og[d], 0, 0, 0);
        og[d] = __builtin_amdgcn_mfma_f32_16x16x32_bf16(ap1, bv1, og[d], 0, 0, 0);
      }
      __builtin_amdgcn_s_setprio(0);
    }

    if (l_act) {
#pragma unroll
      for (int r = 0; r < 4; ++r) {
        int i = q0w + lhi * 4 + r;
        int j = k0 + lrow;
        int d0 = i - j, d1 = d0 - 16, d2 = d0 - 32, d3 = d0 - 48;
        float v0 = (d0 > 64 || d0 < -64) ? NEGINF : sc[0][r] * scl;
        float v1 = (d1 > 64 || d1 < -64) ? NEGINF : sc[1][r] * scl;
        float v2 = (d2 > 64 || d2 < -64) ? NEGINF : sc[2][r] * scl;
        float v3 = (d3 > 64 || d3 < -64) ? NEGINF : sc[3][r] * scl;
        float rmax = fmaxf(fmaxf(v0, v1), fmaxf(v2, v3));
#pragma unroll
        for (int m = 1; m < 16; m <<= 1) rmax = fmaxf(rmax, __shfl_xor(rmax, m, 64));
        float mnew = fmaxf(ml[r], rmax);
        float esc = __expf(ml[r] - mnew);
        float p0 = __expf(v0 - mnew), p1 = __expf(v1 - mnew);
        float p2 = __expf(v2 - mnew), p3 = __expf(v3 - mnew);
        int pr = lhi * 4 + r;
        Pw[w][pr][lrow] = (bf16_t)p0;
        Pw[w][pr][16 + lrow] = (bf16_t)p1;
        Pw[w][pr][32 + lrow] = (bf16_t)p2;
        Pw[w][pr][48 + lrow] = (bf16_t)p3;
        float ps = (p0 + p1) + (p2 + p3);
#pragma unroll
        for (int m = 1; m < 16; m <<= 1) ps += __shfl_xor(ps, m, 64);
        ll[r] = ll[r] * esc + ps;
        ml[r] = mnew;
#pragma unroll
        for (int d = 0; d < 8; ++d) ol[d][r] *= esc;
      }
      bf16x8 ap0 = *(const bf16x8*)(&Pw[w][lrow][lhi * 8]);
      bf16x8 ap1 = *(const bf16x8*)(&Pw[w][lrow][32 + lhi * 8]);
      __builtin_amdgcn_s_setprio(1);
#pragma unroll
      for (int d = 0; d < 8; ++d) {
        int drow = d * 16 + lrow;
        int swz = drow & 7;
        bf16x8 bv0 = *(const bf16x8*)(&Vt[bufc][drow][(lhi ^ swz) * 8]);
        bf16x8 bv1 = *(const bf16x8*)(&Vt[bufc][drow][((4 + lhi) ^ swz) * 8]);
        ol[d] = __builtin_amdgcn_mfma_f32_16x16x32_bf16(ap0, bv0, ol[d], 0, 0, 0);
        ol[d] = __builtin_amdgcn_mfma_f32_16x16x32_bf16(ap1, bv1, ol[d], 0, 0, 0);
      }
      __builtin_amdgcn_s_setprio(0);
    }

    if (more) {
#pragma unroll
      for (int i = 0; i < 4; ++i) {
        int rr = kr + i * 16;
        *(bf16x8*)(&Ks[bufn][rr][(c16 ^ (rr & 7)) * 8]) = kreg[i];
      }
#pragma unroll
      for (int i = 0; i < 4; ++i) {
        int rr = vr + i * 32;
        *(bf16x8*)(&Vt[bufn][rr][(c8 ^ (rr & 7)) * 8]) = vreg[i];
      }
    }
    __syncthreads();
  }

#pragma unroll
  for (int r = 0; r < 4; ++r) {
    int i = q0w + lhi * 4 + r;
    float gv = gates[i];
    float il = 1.f / ll[r], ig = 1.f / lg[r];
#pragma unroll
    for (int d = 0; d < 8; ++d)
      out[(size_t)i * HDIM + h * 128 + d * 16 + lrow] =
          (bf16_t)(gv * ol[d][r] * il + (1.f - gv) * og[d][r] * ig);
  }
}

// ---------------- launch ----------------
extern "C" void kernel_launch(void* const* d_in, const int* in_sizes, int n_in,
                              void* d_out, int out_size, void* d_ws, size_t ws_size,
                              hipStream_t stream) {
  const float* hs  = (const float*)d_in[0];
  const float* Wq  = (const float*)d_in[1];
  const float* Wk  = (const float*)d_in[2];
  const float* Wv  = (const float*)d_in[3];
  const float* Wo  = (const float*)d_in[4];
  const float* gw  = (const float*)d_in[5];
  const float* gb  = (const float*)d_in[6];
  const float* lng = (const float*)d_in[7];
  const float* lnb = (const float*)d_in[8];
  float* out = (float*)d_out;  // reference output dtype is float32

  char* ws = (char*)d_ws;
  bf16_t* hsb   = (bf16_t*)(ws);                    // 2048x2048 bf16 = 8 MB
  bf16_t* wt    = (bf16_t*)(ws + 8388608);          // 3072x2048 bf16 (Wq^T|Wk^T|Wv^T) = 12 MB
  bf16_t* wot   = (bf16_t*)(ws + 20971520);         // 2048x2048 bf16 = 8 MB
  bf16_t* qkv   = (bf16_t*)(ws + 29360128);         // 2048x3072 bf16 = 12 MB
  bf16_t* ao    = (bf16_t*)(ws + 41943040);         // 2048x2048 bf16 = 8 MB
  float*  gates = (float*)(ws + 50331648);          // 2048 fp32 (8 KB)
  bf16_t* vtb   = (bf16_t*)(ws + 50339840);         // V^T [512][2048] bf16 = 2 MB

  // fused LN+gate+cast, merged weight transposes
  ln_gate_cast_kernel<<<2048, 256, 0, stream>>>(hs, gw, gb, lng, lnb, gates, hsb);
  wqkv_trans_kernel<<<dim3(96, 64), 256, 0, stream>>>(Wq, Wk, Wv, wt);
  transpose_cast_kernel<<<dim3(64, 64), 256, 0, stream>>>(Wo, wot, 2048, 2048);
  reg_loss_kernel<<<1, 256, 0, stream>>>(gates, out + (size_t)4194304);

  // fused QKV projection: [S,2048] x [2048,3072] -> [S,3072] (bf16)
  gemm_bt_kernel<bf16_t><<<dim3(24, 16), 256, 0, stream>>>(hsb, wt, qkv, 2048, 3072, 2048);

  // V^T extraction for the attention PV step
  vtrans_kernel<<<dim3(16, 64), 256, 0, stream>>>(qkv, vtb);

  // attention: 512 blocks = 32 chunk-slots x 16 heads, 4 waves each
  attn_kernel<<<dim3(512), 256, 0, stream>>>(qkv, vtb, gates, ao);

  // output projection -> d_out (fp32)
  gemm_bt_kernel<float><<<dim3(16, 16), 256, 0, stream>>>(ao, wot, out, 2048, 2048, 2048);
}